// Round 4
// baseline (429.328 us; speedup 1.0000x reference)
//
#include <hip/hip_runtime.h>

#define SS 128
#define RR 128
#define CC 128
#define SCH 4          // s-slabs marched per block; peeled -> U redundancy 1/SCH
#define EPSF 1e-14f

constexpr int SRC = SS * RR * CC;
constexpr int RC  = RR * CC;

// 9 far loads for one slab's U channels into a named register buffer.
__device__ __forceinline__ void load_u(const float* __restrict__ Up,
                                       float4 (&buf)[9]) {
#pragma unroll
    for (int ch = 0; ch < 9; ++ch)
        buf[ch] = *(const float4*)(Up + ch * SRC);
}

// s-diff between two register-resident slabs.
__device__ __forceinline__ void sdiff9(const float4 (&cur)[9],
                                       const float4 (&prv)[9], float& a_ds) {
#pragma unroll
    for (int ch = 0; ch < 9; ++ch) {
        float d;
        d = cur[ch].x - prv[ch].x; a_ds += d * d;
        d = cur[ch].y - prv[ch].y; a_ds += d * d;
        d = cur[ch].z - prv[ch].z; a_ds += d * d;
        d = cur[ch].w - prv[ch].w; a_ds += d * d;
    }
}

// CO + c-diff + r-diff for one slab whose U is already in registers.
// r-diff: wave w holds rows {2w,2w+1} in its lower/upper 32 lanes, so even
// rows take row+1 from __shfl_down(.,32) (free, intra-wave); odd rows load
// row+1 from global under a half-wave exec mask (half the bytes of R3's vr).
__device__ __forceinline__ void compute_slab(const float4 (&u)[9],
                                             const float* __restrict__ Up,
                                             const float* __restrict__ Lp,
                                             int offr, bool rowOdd,
                                             float wr, float wc,
                                             float& a_dc, float& a_dr,
                                             float& a_co) {
    float4 l0 = *(const float4*)(Lp);
    float4 l1 = *(const float4*)(Lp + SRC);
    float4 l2 = *(const float4*)(Lp + 2 * SRC);
    float L0v[4] = {l0.x, l0.y, l0.z, l0.w};
    float L1v[4] = {l1.x, l1.y, l1.z, l1.w};
    float L2v[4] = {l2.x, l2.y, l2.z, l2.w};
    int idx[4];
#pragma unroll
    for (int j = 0; j < 4; ++j) {
        int id = 0;
        float best = L0v[j];
        if (L1v[j] > best) { best = L1v[j]; id = 1; }
        if (L2v[j] > best) { best = L2v[j]; id = 2; }
        idx[j] = id;
    }

    float am[3][4];
#pragma unroll
    for (int g = 0; g < 3; ++g)
#pragma unroll
        for (int j = 0; j < 4; ++j) am[g][j] = 0.f;

    float t_dcb = 0.f, t_dr = 0.f;

#pragma unroll
    for (int ch = 0; ch < 9; ++ch) {
        float4 uu = u[ch];

        // r-diff source: shfl for even rows, masked global load for odd rows
        float4 vr;
        vr.x = __shfl_down(uu.x, 32);
        vr.y = __shfl_down(uu.y, 32);
        vr.z = __shfl_down(uu.z, 32);
        vr.w = __shfl_down(uu.w, 32);
        if (rowOdd) vr = *(const float4*)(Up + ch * SRC + offr);

        int g = ch / 3, m = ch % 3;
        float uuv[4] = {uu.x, uu.y, uu.z, uu.w};
#pragma unroll
        for (int j = 0; j < 4; ++j)
            if (idx[j] == m) am[g][j] = fabsf(uuv[j]);

        float d;
        d = uu.y - uu.x; a_dc += d * d;
        d = uu.z - uu.y; a_dc += d * d;
        d = uu.w - uu.z; a_dc += d * d;
        float un = __shfl_down(uu.x, 1);      // lanes 31/63 masked by wc
        d = un - uu.w; t_dcb += d * d;

        d = vr.x - uu.x; t_dr += d * d;
        d = vr.y - uu.y; t_dr += d * d;
        d = vr.z - uu.z; t_dr += d * d;
        d = vr.w - uu.w; t_dr += d * d;
    }
    a_dc += wc * t_dcb;
    a_dr += wr * t_dr;

#pragma unroll
    for (int j = 0; j < 4; ++j) {
        float e1 = am[0][j], e2 = am[1][j], e3 = am[2][j];
        float den = fmaxf(e1 * e1 + e2 * e2 + e3 * e3, EPSF);
        float num = 0.5f * ((e1 - e2) * (e1 - e2) + (e2 - e3) * (e2 - e3) +
                            (e3 - e1) * (e3 - e1));
        a_co += sqrtf(num / den);
    }
}

// Block = 256 threads = 8 rows x 32 float4-cols, marching SCH=4 s-slabs with
// an explicit A/B register double-buffer (structure identical to R3); only the
// r-diff sourcing changed (shfl / half-wave load). 1024 blocks = 4 blocks/CU.
__global__ __launch_bounds__(256, 4) void scol_main(const float* __restrict__ L,
                                                    const float* __restrict__ U,
                                                    float4* __restrict__ part) {
    // bijective XCD swizzle (grid 1024, divisible by 8): consecutive logical
    // blocks (rt fastest, then sc) share an XCD L2.
    int bid = blockIdx.x;
    int cpx = gridDim.x >> 3;
    int swz = (bid & 7) * cpx + (bid >> 3);

    int rt = swz & 15;            // r-tile: 16 tiles of 8 rows
    int sc = (swz >> 4) & 31;     // s-chunk: 32 chunks of SCH=4
    int b  = swz >> 9;            // batch

    int tid = threadIdx.x;
    int c4       = tid & 31;
    int rowLocal = tid >> 5;      // 0..7; wave w = rows {2w, 2w+1}
    bool rowOdd  = (tid & 32) != 0;
    int r  = (rt << 3) + rowLocal;
    int s0 = sc * SCH;
    int c  = c4 << 2;

    bool hr = (r < RR - 1), hc = (c4 < 31);
    float wr = hr ? 1.f : 0.f;
    float wc = hc ? 1.f : 0.f;
    int offr = hr ? CC : 0;       // clamped: boundary re-loads self, weight 0
    // chunk-boundary slab: clamped to self -> sdiff contributes exactly 0
    int offb = (s0 + SCH < SS) ? SCH * RC : (SCH - 1) * RC;

    int pos = (s0 * RR + r) * CC + c;
    const float* Ub = U + (size_t)b * 9 * SRC + pos;
    const float* Lb = L + (size_t)b * 3 * SRC + pos;

    float a_dc = 0.f, a_dr = 0.f, a_ds = 0.f, a_co = 0.f;

    float4 A[9], B[9];

    // ---- software-pipelined 4-slab chain ----
    load_u(Ub, A);                                    // slab 0
    load_u(Ub + RC, B);                               // prefetch slab 1
    compute_slab(A, Ub, Lb, offr, rowOdd, wr, wc, a_dc, a_dr, a_co);

    sdiff9(B, A, a_ds);                               // slab1 - slab0; A free
    load_u(Ub + 2 * RC, A);                           // prefetch slab 2
    compute_slab(B, Ub + RC, Lb + RC, offr, rowOdd, wr, wc, a_dc, a_dr, a_co);

    sdiff9(A, B, a_ds);                               // slab2 - slab1; B free
    load_u(Ub + 3 * RC, B);                           // prefetch slab 3
    compute_slab(A, Ub + 2 * RC, Lb + 2 * RC, offr, rowOdd, wr, wc,
                 a_dc, a_dr, a_co);

    sdiff9(B, A, a_ds);                               // slab3 - slab2; A free
    load_u(Ub + offb, A);                             // prefetch boundary slab
    compute_slab(B, Ub + 3 * RC, Lb + 3 * RC, offr, rowOdd, wr, wc,
                 a_dc, a_dr, a_co);

    sdiff9(A, B, a_ds);                               // boundary (0 if clamped)

    // ---------- wave reduce (64 lanes) ----------
#pragma unroll
    for (int off = 32; off > 0; off >>= 1) {
        a_co += __shfl_down(a_co, off);
        a_ds += __shfl_down(a_ds, off);
        a_dr += __shfl_down(a_dr, off);
        a_dc += __shfl_down(a_dc, off);
    }

    __shared__ float s_co[4], s_ds[4], s_dr[4], s_dc[4];
    int wid  = threadIdx.x >> 6;
    int lane = threadIdx.x & 63;
    if (lane == 0) {
        s_co[wid] = a_co; s_ds[wid] = a_ds;
        s_dr[wid] = a_dr; s_dc[wid] = a_dc;
    }
    __syncthreads();
    if (threadIdx.x == 0) {
        float t_co = 0.f, t_s = 0.f, t_r = 0.f, t_c = 0.f;
        for (int w = 0; w < 4; ++w) {
            t_co += s_co[w]; t_s += s_ds[w];
            t_r += s_dr[w]; t_c += s_dc[w];
        }
        part[blockIdx.x] = make_float4(t_co, t_s, t_r, t_c);
    }
}

// Single block: reduce nblk float4 partials in double, emit the scalar.
__global__ __launch_bounds__(256) void scol_final(const float4* __restrict__ part,
                                                  float* __restrict__ out,
                                                  int nblk, int B) {
    double d_co = 0., d_ds = 0., d_dr = 0., d_dc = 0.;
    for (int i = threadIdx.x; i < nblk; i += blockDim.x) {
        float4 p = part[i];
        d_co += (double)p.x; d_ds += (double)p.y;
        d_dr += (double)p.z; d_dc += (double)p.w;
    }
#pragma unroll
    for (int off = 32; off > 0; off >>= 1) {
        d_co += __shfl_down(d_co, off);
        d_ds += __shfl_down(d_ds, off);
        d_dr += __shfl_down(d_dr, off);
        d_dc += __shfl_down(d_dc, off);
    }
    __shared__ double sh[4][4];
    int wid  = threadIdx.x >> 6;
    int lane = threadIdx.x & 63;
    if (lane == 0) {
        sh[wid][0] = d_co; sh[wid][1] = d_ds;
        sh[wid][2] = d_dr; sh[wid][3] = d_dc;
    }
    __syncthreads();
    if (threadIdx.x == 0) {
        double t_co = 0., t_ds = 0., t_dr = 0., t_dc = 0.;
        for (int w = 0; w < 4; ++w) {
            t_co += sh[w][0]; t_ds += sh[w][1];
            t_dr += sh[w][2]; t_dc += sh[w][3];
        }
        double nvox = (double)B * SS * RR * CC;
        double nds  = (double)B * (SS - 1) * RR * CC;
        double ndr  = (double)B * SS * (RR - 1) * CC;
        double ndc  = (double)B * SS * RR * (CC - 1);
        out[0] = (float)(0.5 * (t_co / nvox + t_ds / nds + t_dr / ndr + t_dc / ndc));
    }
}

extern "C" void kernel_launch(void* const* d_in, const int* in_sizes, int n_in,
                              void* d_out, int out_size, void* d_ws, size_t ws_size,
                              hipStream_t stream) {
    const float* L = (const float*)d_in[0];
    const float* U = (const float*)d_in[1];
    float* out = (float*)d_out;

    int B = in_sizes[1] / (9 * SS * RR * CC);
    int blocks = B * (SS / SCH) * (RR / 8);   // 1024 for B=2: 4 blocks/CU exact

    float4* part = (float4*)d_ws;

    hipLaunchKernelGGL(scol_main, dim3(blocks), dim3(256), 0, stream,
                       L, U, part);
    hipLaunchKernelGGL(scol_final, dim3(1), dim3(256), 0, stream,
                       part, out, blocks, B);
}

// Round 5
// 279.540 us; speedup vs baseline: 1.5358x; 1.5358x over previous
//
#include <hip/hip_runtime.h>

#define SS 128
#define RR 128
#define CC 128
#define EPSF 1e-14f

constexpr int SRC = SS * RR * CC;
constexpr int RC  = RR * CC;

// ---------------------------------------------------------------------------
// Kernel 1: CO gather. R0-proven structure: 12 batched dwordx4 loads/thread
// (3 L + 9 U at the same voxel), no diffs, no re-reads. 201 MB compulsory.
// ---------------------------------------------------------------------------
__global__ __launch_bounds__(256, 4) void co_gather(const float* __restrict__ L,
                                                    const float* __restrict__ U,
                                                    float4* __restrict__ part) {
    // bijective XCD swizzle (grid B*2048, divisible by 8)
    int bid = blockIdx.x;
    int cpx = gridDim.x >> 3;
    int swz = (bid & 7) * cpx + (bid >> 3);

    int tid = threadIdx.x;
    int c4  = tid & 31;
    int row = swz * 8 + (tid >> 5);     // (b*S + s)*R + r
    int b   = row >> 14;                // row / (S*R)
    int c   = c4 << 2;

    int pos    = (row - b * (SS * RR)) * CC + c;
    const float* Lb = L + (size_t)b * 3 * SRC + pos;
    const float* Ub = U + (size_t)b * 9 * SRC + pos;

    // ---- batched load phase: 12 x global_load_dwordx4 ----
    float4 l0 = *(const float4*)(Lb);
    float4 l1 = *(const float4*)(Lb + SRC);
    float4 l2 = *(const float4*)(Lb + 2 * SRC);
    float4 u[9];
#pragma unroll
    for (int ch = 0; ch < 9; ++ch)
        u[ch] = *(const float4*)(Ub + ch * SRC);

    // ---- compute ----
    float L0v[4] = {l0.x, l0.y, l0.z, l0.w};
    float L1v[4] = {l1.x, l1.y, l1.z, l1.w};
    float L2v[4] = {l2.x, l2.y, l2.z, l2.w};
    int idx[4];
#pragma unroll
    for (int j = 0; j < 4; ++j) {
        int id = 0;
        float best = L0v[j];
        if (L1v[j] > best) { best = L1v[j]; id = 1; }  // strict: first-max wins
        if (L2v[j] > best) { best = L2v[j]; id = 2; }
        idx[j] = id;
    }

    float am[3][4];
#pragma unroll
    for (int g = 0; g < 3; ++g)
#pragma unroll
        for (int j = 0; j < 4; ++j) am[g][j] = 0.f;

#pragma unroll
    for (int ch = 0; ch < 9; ++ch) {
        int g = ch / 3, m = ch % 3;
        float uuv[4] = {u[ch].x, u[ch].y, u[ch].z, u[ch].w};
#pragma unroll
        for (int j = 0; j < 4; ++j)
            if (idx[j] == m) am[g][j] = fabsf(uuv[j]);
    }

    float a_co = 0.f;
#pragma unroll
    for (int j = 0; j < 4; ++j) {
        float e1 = am[0][j], e2 = am[1][j], e3 = am[2][j];
        float den = fmaxf(e1 * e1 + e2 * e2 + e3 * e3, EPSF);
        float num = 0.5f * ((e1 - e2) * (e1 - e2) + (e2 - e3) * (e2 - e3) +
                            (e3 - e1) * (e3 - e1));
        a_co += sqrtf(num / den);
    }

    // ---- wave + block reduce ----
#pragma unroll
    for (int off = 32; off > 0; off >>= 1)
        a_co += __shfl_down(a_co, off);

    __shared__ float s_co[4];
    int wid  = threadIdx.x >> 6;
    int lane = threadIdx.x & 63;
    if (lane == 0) s_co[wid] = a_co;
    __syncthreads();
    if (threadIdx.x == 0)
        part[blockIdx.x] =
            make_float4(s_co[0] + s_co[1] + s_co[2] + s_co[3], 0.f, 0.f, 0.f);
}

// ---------------------------------------------------------------------------
// Kernel 2: gradient stream. One block = one (volume, 8-row tile, 8-slab
// chunk). Thread marches 8 slabs along s: s-diff from registers (free),
// c-diff via shfl (free), r-diff via LDS row-exchange; only row-7 threads
// issue one small global load per slab (row 8, L2-warm from neighbor tile).
// Live state is tiny (cur/nxt/prev) -> no spill risk from the masked load.
// ---------------------------------------------------------------------------
__global__ __launch_bounds__(256, 4) void grad_stream(const float* __restrict__ U,
                                                      float4* __restrict__ part) {
    // bijective XCD swizzle (grid B*9*256, divisible by 8 for B=2)
    int bid = blockIdx.x;
    int cpx = gridDim.x >> 3;
    int swz = (bid & 7) * cpx + (bid >> 3);

    int rt  = swz & 15;          // r-tile: 16 tiles of 8 rows
    int sc  = (swz >> 4) & 15;   // s-chunk: 16 chunks of 8 slabs
    int vol = swz >> 8;          // 0..B*9-1 (U volumes are contiguous)

    int tid  = threadIdx.x;
    int c4   = tid & 31;
    int rowL = tid >> 5;         // 0..7
    int r    = (rt << 3) + rowL;
    int s0   = sc << 3;
    int c    = c4 << 2;

    bool hr = (r < RR - 1), hc = (c4 < 31);
    float wr = hr ? 1.f : 0.f;
    float wc = hc ? 1.f : 0.f;
    int offr = hr ? CC : 0;                         // clamped self-load, wr=0
    int offb = (s0 + 8 < SS) ? 8 * RC : 7 * RC;     // clamped -> zero s-diff

    const float* V = U + (size_t)vol * SRC + ((size_t)s0 * RR + r) * CC + c;

    __shared__ float4 lds[2][8][32];                // 8 KB, double-buffered

    float a_ds = 0.f, a_dr = 0.f, a_dc = 0.f;

    float4 cur = *(const float4*)V;
    float4 prev = cur;

#pragma unroll
    for (int ss = 0; ss < 8; ++ss) {
        int no = (ss == 7) ? offb : (ss + 1) * RC;
        float4 nxt = *(const float4*)(V + no);      // prefetch next slab

        float4 vr7 = cur;                           // defined for all lanes
        if (rowL == 7)                              // one masked small load
            vr7 = *(const float4*)(V + ss * RC + offr);

        lds[ss & 1][rowL][c4] = cur;
        __syncthreads();
        float4 vr = (rowL < 7) ? lds[ss & 1][rowL + 1][c4] : vr7;

        float d;
        // c-diffs (3 internal + boundary via shfl; lanes c4==31 masked by wc)
        d = cur.y - cur.x; a_dc += d * d;
        d = cur.z - cur.y; a_dc += d * d;
        d = cur.w - cur.z; a_dc += d * d;
        float un = __shfl_down(cur.x, 1);
        d = un - cur.w; a_dc += wc * (d * d);

        // r-diff
        float tr = 0.f;
        d = vr.x - cur.x; tr += d * d;
        d = vr.y - cur.y; tr += d * d;
        d = vr.z - cur.z; tr += d * d;
        d = vr.w - cur.w; tr += d * d;
        a_dr += wr * tr;

        // s-diff vs previous slab (ss==0's pair belongs to previous chunk)
        if (ss > 0) {
            d = cur.x - prev.x; a_ds += d * d;
            d = cur.y - prev.y; a_ds += d * d;
            d = cur.z - prev.z; a_ds += d * d;
            d = cur.w - prev.w; a_ds += d * d;
        }
        prev = cur;
        cur  = nxt;
    }
    // chunk-boundary s-diff: cur = slab s0+8 (clamped clone -> exactly 0)
    {
        float d;
        d = cur.x - prev.x; a_ds += d * d;
        d = cur.y - prev.y; a_ds += d * d;
        d = cur.z - prev.z; a_ds += d * d;
        d = cur.w - prev.w; a_ds += d * d;
    }

    // ---- wave + block reduce ----
#pragma unroll
    for (int off = 32; off > 0; off >>= 1) {
        a_ds += __shfl_down(a_ds, off);
        a_dr += __shfl_down(a_dr, off);
        a_dc += __shfl_down(a_dc, off);
    }

    __shared__ float s_ds[4], s_dr[4], s_dc[4];
    int wid  = threadIdx.x >> 6;
    int lane = threadIdx.x & 63;
    if (lane == 0) { s_ds[wid] = a_ds; s_dr[wid] = a_dr; s_dc[wid] = a_dc; }
    __syncthreads();
    if (threadIdx.x == 0)
        part[blockIdx.x] = make_float4(0.f,
                                       s_ds[0] + s_ds[1] + s_ds[2] + s_ds[3],
                                       s_dr[0] + s_dr[1] + s_dr[2] + s_dr[3],
                                       s_dc[0] + s_dc[1] + s_dc[2] + s_dc[3]);
}

// ---------------------------------------------------------------------------
// Final: reduce all float4 partials (co blocks wrote .x, grad blocks .y/.z/.w)
// ---------------------------------------------------------------------------
__global__ __launch_bounds__(256) void scol_final(const float4* __restrict__ part,
                                                  float* __restrict__ out,
                                                  int nblk, int B) {
    double d_co = 0., d_ds = 0., d_dr = 0., d_dc = 0.;
    for (int i = threadIdx.x; i < nblk; i += blockDim.x) {
        float4 p = part[i];
        d_co += (double)p.x; d_ds += (double)p.y;
        d_dr += (double)p.z; d_dc += (double)p.w;
    }
#pragma unroll
    for (int off = 32; off > 0; off >>= 1) {
        d_co += __shfl_down(d_co, off);
        d_ds += __shfl_down(d_ds, off);
        d_dr += __shfl_down(d_dr, off);
        d_dc += __shfl_down(d_dc, off);
    }
    __shared__ double sh[4][4];
    int wid  = threadIdx.x >> 6;
    int lane = threadIdx.x & 63;
    if (lane == 0) {
        sh[wid][0] = d_co; sh[wid][1] = d_ds;
        sh[wid][2] = d_dr; sh[wid][3] = d_dc;
    }
    __syncthreads();
    if (threadIdx.x == 0) {
        double t_co = 0., t_ds = 0., t_dr = 0., t_dc = 0.;
        for (int w = 0; w < 4; ++w) {
            t_co += sh[w][0]; t_ds += sh[w][1];
            t_dr += sh[w][2]; t_dc += sh[w][3];
        }
        double nvox = (double)B * SS * RR * CC;
        double nds  = (double)B * (SS - 1) * RR * CC;
        double ndr  = (double)B * SS * (RR - 1) * CC;
        double ndc  = (double)B * SS * RR * (CC - 1);
        out[0] = (float)(0.5 * (t_co / nvox + t_ds / nds + t_dr / ndr + t_dc / ndc));
    }
}

extern "C" void kernel_launch(void* const* d_in, const int* in_sizes, int n_in,
                              void* d_out, int out_size, void* d_ws, size_t ws_size,
                              hipStream_t stream) {
    const float* L = (const float*)d_in[0];
    const float* U = (const float*)d_in[1];
    float* out = (float*)d_out;

    int B = in_sizes[1] / (9 * SS * RR * CC);
    int blocks_co   = B * SS * RR / 8;        // 4096 for B=2
    int blocks_grad = B * 9 * 16 * 16;        // 4608 for B=2
    int nblk = blocks_co + blocks_grad;       // 8704 float4 partials

    float4* part = (float4*)d_ws;

    hipLaunchKernelGGL(co_gather, dim3(blocks_co), dim3(256), 0, stream,
                       L, U, part);
    hipLaunchKernelGGL(grad_stream, dim3(blocks_grad), dim3(256), 0, stream,
                       U, part + blocks_co);
    hipLaunchKernelGGL(scol_final, dim3(1), dim3(256), 0, stream,
                       part, out, nblk, B);
}